// Round 5
// baseline (47.342 us; speedup 1.0000x reference)
//
#include <hip/hip_runtime.h>
#include <stdint.h>

#define HW   56
#define CH   64
#define PIX  (HW*HW)       // 3136
#define NPIX (4*PIX)       // 12544
#define KS   7
#define PAD  3

typedef __attribute__((ext_vector_type(8))) short short8;
typedef __attribute__((ext_vector_type(4))) float f32x4;

__device__ __forceinline__ uint32_t rne_bf16(float v) {
    uint32_t u = __float_as_uint(v);
    return (u + 0x7FFFu + ((u >> 16) & 1u)) >> 16;
}
__device__ __forceinline__ void split_bf16(float v, short& hi, short& lo) {
    uint32_t h = rne_bf16(v);
    float hf = __uint_as_float(h << 16);
    hi = (short)h;
    lo = (short)rne_bf16(v - hf);
}

// ---- kernel 0: split W into bf16 hi/lo, MFMA fragment order (once) ---------
// frag layout (short8 units): [m][cot][ch][part][lane]  -> coalesced dwordx4
// grid 3 x 256 = 768 jobs = 3 m * 4 cot * 64 lanes.
__global__ __launch_bounds__(256) void wfrag_k(
    const float* __restrict__ Wq, const float* __restrict__ Wk,
    const float* __restrict__ Wv, short8* __restrict__ frag)
{
    const int id  = blockIdx.x * 256 + threadIdx.x;   // 0..767
    const int m   = id >> 8;
    const int cot = (id >> 6) & 3;
    const int l   = id & 63;
    const float* __restrict__ Wm = (m == 0) ? Wq : (m == 1) ? Wk : Wv;
    const int lr = l & 15, koff = (l >> 4) * 8;

    #pragma unroll
    for (int ch = 0; ch < 2; ++ch) {
        short8 h, lo;
        #pragma unroll
        for (int j = 0; j < 8; ++j) {
            short hh, ll;
            split_bf16(Wm[(cot * 16 + lr) * 64 + ch * 32 + koff + j], hh, ll);
            h[j] = hh; lo[j] = ll;
        }
        const int base = (((m * 4 + cot) * 2 + ch) * 2 + 0) * 64 + l;
        frag[base]      = h;      // part 0 = hi
        frag[base + 64] = lo;     // part 1 = lo
    }
}

// ---- kernel 1: q/k/v = 1x1 conv via split-bf16 MFMA ------------------------
// grid 588 = 3 mats * 4 b * 49 chunks(64 px), block 256 (4 waves).
// out layout [b][hw][c] fp32. C-layout per round-3 validated mapping.
__global__ __launch_bounds__(256) void qkv_gemm(
    const float* __restrict__ x, const short8* __restrict__ frag,
    float* __restrict__ qT, float* __restrict__ kT, float* __restrict__ vT)
{
    __shared__ float xs[64 * 69];          // [px][ci], stride 69 -> conflict-free
    const int t   = threadIdx.x;
    const int mat = blockIdx.x / 196;
    const int rem = blockIdx.x % 196;
    const int b   = rem / 49;
    const int hw0 = (rem % 49) * 64;

    #pragma unroll
    for (int i = 0; i < 16; ++i) {         // coalesced 256B row reads
        int idx = t + i * 256;
        int px = idx & 63, ci = idx >> 6;
        xs[px * 69 + ci] = x[(b * CH + ci) * PIX + hw0 + px];
    }
    __syncthreads();

    const int l = t & 63, w = t >> 6;
    const int lr = l & 15, lk = l >> 4, koff = lk * 8;
    const int arow = w * 16 + lr;

    short8 aH[2], aL[2];
    #pragma unroll
    for (int ch = 0; ch < 2; ++ch) {
        short8 h, lo;
        #pragma unroll
        for (int j = 0; j < 8; ++j) {
            short hh, ll;
            split_bf16(xs[arow * 69 + ch * 32 + koff + j], hh, ll);
            h[j] = hh; lo[j] = ll;
        }
        aH[ch] = h; aL[ch] = lo;
    }

    float* __restrict__ outp = (mat == 0) ? qT : (mat == 1) ? kT : vT;
    const int prow = w * 16 + lk * 4;

    #pragma unroll
    for (int cot = 0; cot < 4; ++cot) {
        const int fb = ((mat * 4 + cot) * 2) * 2 * 64 + l;  // ch0,part0
        short8 bh0 = frag[fb];
        short8 bl0 = frag[fb + 64];
        short8 bh1 = frag[fb + 128];
        short8 bl1 = frag[fb + 192];
        f32x4 a = {0.f, 0.f, 0.f, 0.f};
        a = __builtin_amdgcn_mfma_f32_16x16x32_bf16(aL[0], bh0, a, 0, 0, 0);
        a = __builtin_amdgcn_mfma_f32_16x16x32_bf16(aH[0], bl0, a, 0, 0, 0);
        a = __builtin_amdgcn_mfma_f32_16x16x32_bf16(aH[0], bh0, a, 0, 0, 0);
        a = __builtin_amdgcn_mfma_f32_16x16x32_bf16(aL[1], bh1, a, 0, 0, 0);
        a = __builtin_amdgcn_mfma_f32_16x16x32_bf16(aH[1], bl1, a, 0, 0, 0);
        a = __builtin_amdgcn_mfma_f32_16x16x32_bf16(aH[1], bh1, a, 0, 0, 0);
        const int co = cot * 16 + lr;
        #pragma unroll
        for (int r = 0; r < 4; ++r)
            outp[(size_t)(b * PIX + hw0 + prow + r) * 64 + co] = a[r];
    }
}

// ---- kernel 2: windowed per-channel attention ------------------------------
// grid 784 = 4 b * 14*14 tiles of 4x4, block 256 (4 waves), 52 KB LDS -> 3/CU.
#define TT 4
#define HALOW 10
#define HP (HALOW*HALOW)   // 100

__global__ __launch_bounds__(256) void attn_k(
    const float* __restrict__ qT, const float* __restrict__ kT,
    const float* __restrict__ vT, const float* __restrict__ rel_h,
    const float* __restrict__ rel_w, float* __restrict__ out)
{
    __shared__ float2 kvs[HP * 65];        // 52,000 B
    const int t    = threadIdx.x;
    const int b    = blockIdx.x / 196;
    const int tile = blockIdx.x % 196;
    const int ty0  = (tile / 14) * TT;
    const int tx0  = (tile % 14) * TT;
    const int c    = t & 63;
    const int oy   = t >> 6;               // 0..3, wave-uniform

    float qv[TT];
    #pragma unroll
    for (int ox = 0; ox < TT; ++ox)
        qv[ox] = qT[(b * PIX + (ty0 + oy) * HW + tx0 + ox) * 64 + c];

    const bool is_h = (c < 32);
    float relv[KS];
    #pragma unroll
    for (int j = 0; j < KS; ++j)
        relv[j] = is_h ? rel_h[c * KS + j] : rel_w[(c - 32) * KS + j];

    for (int idx = t; idx < HP * 64; idx += 256) {
        int cc = idx & 63, p = idx >> 6;
        int hy = ty0 + p / HALOW - PAD;
        int hx = tx0 + p % HALOW - PAD;
        bool ok = (hy >= 0) & (hy < HW) & (hx >= 0) & (hx < HW);
        int g = (b * PIX + hy * HW + hx) * 64 + cc;   // coalesced
        float kk = ok ? kT[g] : 0.f;
        float vvv = ok ? vT[g] : 0.f;
        kvs[p * 65 + cc] = make_float2(kk, vvv);
    }
    __syncthreads();

    float sum[TT] = {0.f, 0.f, 0.f, 0.f};
    float acc[TT] = {0.f, 0.f, 0.f, 0.f};
    #pragma unroll
    for (int kh = 0; kh < KS; ++kh) {
        float2 row[HALOW];
        #pragma unroll
        for (int ii = 0; ii < HALOW; ++ii)
            row[ii] = kvs[((oy + kh) * HALOW + ii) * 65 + c];
        const float rh = relv[kh];
        #pragma unroll
        for (int ox = 0; ox < TT; ++ox) {
            #pragma unroll
            for (int kw = 0; kw < KS; ++kw) {
                float2 f = row[ox + kw];
                float e = __expf(qv[ox] * f.x);
                sum[ox] += e;
                acc[ox] = fmaf(e, f.y + (is_h ? rh : relv[kw]), acc[ox]);
            }
        }
    }

    __syncthreads();                       // kvs reads done; reuse as transpose buf
    float* os = (float*)&kvs[0];
    #pragma unroll
    for (int ox = 0; ox < TT; ++ox)
        os[(oy * TT + ox) * 67 + c] = acc[ox] / sum[ox];
    __syncthreads();
    #pragma unroll
    for (int k = 0; k < 4; ++k) {
        int idx = t + k * 256;
        int p = idx & 15, cc = idx >> 4;
        out[(b * CH + cc) * PIX + (ty0 + (p >> 2)) * HW + tx0 + (p & 3)] =
            os[p * 67 + cc];
    }
}

// ---- fallback (ws too small): naive fused ---------------------------------
__global__ __launch_bounds__(256) void naive_kernel(
    const float* __restrict__ x,  const float* __restrict__ Wq,
    const float* __restrict__ Wk, const float* __restrict__ Wv,
    const float* __restrict__ rel_h, const float* __restrict__ rel_w,
    float* __restrict__ out)
{
    int idx = blockIdx.x * 256 + threadIdx.x;
    if (idx >= NPIX * CH) return;
    int wpx = idx % HW;
    int hpx = (idx / HW) % HW;
    int c   = (idx / PIX) % CH;
    int b   = idx / (PIX * CH);
    const float* xb = x + (size_t)b * CH * PIX;

    float q = 0.f;
    for (int ci = 0; ci < CH; ++ci)
        q += Wq[c * CH + ci] * xb[ci * PIX + hpx * HW + wpx];

    float sum = 0.f, acc = 0.f;
    #pragma unroll
    for (int kh = 0; kh < KS; ++kh)
        #pragma unroll
        for (int kw = 0; kw < KS; ++kw) {
            int y = hpx + kh - PAD, xx = wpx + kw - PAD;
            float kv = 0.f, vv = 0.f;
            if (y >= 0 && y < HW && xx >= 0 && xx < HW)
                for (int ci = 0; ci < CH; ++ci) {
                    float xvv = xb[ci * PIX + y * HW + xx];
                    kv += Wk[c * CH + ci] * xvv;
                    vv += Wv[c * CH + ci] * xvv;
                }
            vv += (c < 32) ? rel_h[c * KS + kh] : rel_w[(c - 32) * KS + kw];
            float e = __expf(q * kv);
            sum += e;
            acc += e * vv;
        }
    out[idx] = acc / sum;
}

extern "C" void kernel_launch(void* const* d_in, const int* in_sizes, int n_in,
                              void* d_out, int out_size, void* d_ws, size_t ws_size,
                              hipStream_t stream) {
    const float* x     = (const float*)d_in[0];
    const float* Wq    = (const float*)d_in[1];
    const float* Wk    = (const float*)d_in[2];
    const float* Wv    = (const float*)d_in[3];
    const float* rel_h = (const float*)d_in[4];
    const float* rel_w = (const float*)d_in[5];
    float* out = (float*)d_out;

    const size_t arr  = (size_t)NPIX * CH;                    // 802816 floats
    const size_t need = 3 * arr * sizeof(float) + 49152;      // qkv + W frags

    if (ws_size >= need) {
        float* qT = (float*)d_ws;
        float* kT = qT + arr;
        float* vT = kT + arr;
        short8* frag = (short8*)(vT + arr);
        wfrag_k<<<3, 256, 0, stream>>>(Wq, Wk, Wv, frag);
        qkv_gemm<<<588, 256, 0, stream>>>(x, frag, qT, kT, vT);
        attn_k<<<784, 256, 0, stream>>>(qT, kT, vT, rel_h, rel_w, out);
    } else {
        naive_kernel<<<(NPIX * CH + 255) / 256, 256, 0, stream>>>(
            x, Wq, Wk, Wv, rel_h, rel_w, out);
    }
}